// Round 7
// baseline (1244.691 us; speedup 1.0000x reference)
//
#include <hip/hip_runtime.h>
#include <hip/hip_bf16.h>
#include <cmath>

#define NN 100000
#define NE 1600000
#define FIN 512
#define HD 128
#define NC 40
#define NL 8

typedef __attribute__((ext_vector_type(8))) short bh8;
typedef __attribute__((ext_vector_type(4))) float f4;
typedef __attribute__((ext_vector_type(4))) unsigned int u4;
typedef __attribute__((ext_vector_type(2))) unsigned int u2;

__device__ __forceinline__ float bflo(unsigned p){ return __uint_as_float(p << 16); }
__device__ __forceinline__ float bfhi(unsigned p){ return __uint_as_float(p & 0xffff0000u); }
__device__ __forceinline__ unsigned short f2bf(float f){
  unsigned u = __float_as_uint(f);
  u += 0x7fffu + ((u >> 16) & 1u);
  return (unsigned short)(u >> 16);
}
__device__ __forceinline__ unsigned pack2(float a, float b){
  return (unsigned)f2bf(a) | ((unsigned)f2bf(b) << 16);
}

// ---------------- CSR build ----------------
__global__ void k_deg(const int* __restrict__ dst, int* __restrict__ deg, int e){
  for (int i = blockIdx.x * blockDim.x + threadIdx.x; i < e; i += gridDim.x * blockDim.x)
    atomicAdd(&deg[dst[i]], 1);
}

__global__ void k_scan(const int* __restrict__ deg, int* __restrict__ offs,
                       int* __restrict__ cur, int n){
  __shared__ int wsum[16];
  __shared__ int carry;
  int t = threadIdx.x, lane = t & 63, wid = t >> 6;
  if (t == 0) carry = 0;
  __syncthreads();
  for (int base = 0; base < n; base += 1024){
    int idx = base + t;
    int v = (idx < n) ? deg[idx] : 0;
    int orig = v;
    #pragma unroll
    for (int off = 1; off < 64; off <<= 1){
      int u = __shfl_up(v, off);
      if (lane >= off) v += u;
    }
    if (lane == 63) wsum[wid] = v;
    __syncthreads();
    if (wid == 0){
      int s = (lane < 16) ? wsum[lane] : 0;
      #pragma unroll
      for (int off = 1; off < 16; off <<= 1){
        int u = __shfl_up(s, off);
        if (lane >= off) s += u;
      }
      if (lane < 16) wsum[lane] = s;
    }
    __syncthreads();
    int wexcl = (wid == 0) ? 0 : wsum[wid - 1];
    int excl = carry + wexcl + (v - orig);
    if (idx < n){ offs[idx] = excl; cur[idx] = excl; }
    int ctot = wsum[15];
    __syncthreads();
    if (t == 0) carry += ctot;
    __syncthreads();
  }
  if (t == 0) offs[n] = carry;
}

__global__ void k_scatter(const int* __restrict__ src, const int* __restrict__ dst,
                          const float* __restrict__ w, int* __restrict__ cur,
                          u2* __restrict__ epk, int e){
  int stride = gridDim.x * blockDim.x;
  int i = blockIdx.x * blockDim.x + threadIdx.x;
  for (; i + 3 * stride < e; i += 4 * stride){
    int i0 = i, i1 = i + stride, i2 = i + 2 * stride, i3 = i + 3 * stride;
    int d0 = dst[i0], d1 = dst[i1], d2 = dst[i2], d3 = dst[i3];
    int p0 = atomicAdd(&cur[d0], 1);
    int p1 = atomicAdd(&cur[d1], 1);
    int p2 = atomicAdd(&cur[d2], 1);
    int p3 = atomicAdd(&cur[d3], 1);
    u2 v0 = { (unsigned)src[i0], __float_as_uint(w[i0]) };
    u2 v1 = { (unsigned)src[i1], __float_as_uint(w[i1]) };
    u2 v2 = { (unsigned)src[i2], __float_as_uint(w[i2]) };
    u2 v3 = { (unsigned)src[i3], __float_as_uint(w[i3]) };
    __builtin_nontemporal_store(v0, &epk[p0]);
    __builtin_nontemporal_store(v1, &epk[p1]);
    __builtin_nontemporal_store(v2, &epk[p2]);
    __builtin_nontemporal_store(v3, &epk[p3]);
  }
  for (; i < e; i += stride){
    int d = dst[i];
    int p = atomicAdd(&cur[d], 1);
    u2 v = { (unsigned)src[i], __float_as_uint(w[i]) };
    __builtin_nontemporal_store(v, &epk[p]);
  }
}

// ---------------- weight transpose+cast: out[c][k] = bf16(in[k][c]) ----------------
__global__ void k_twt(const float* __restrict__ in, unsigned short* __restrict__ out,
                      int K, int C, int Cpad){
  int total = Cpad * K;
  for (int i = blockIdx.x * blockDim.x + threadIdx.x; i < total; i += gridDim.x * blockDim.x){
    int c = i / K, k = i % K;
    float v = (c < C) ? in[(size_t)k * C + c] : 0.f;
    out[i] = f2bf(v);
  }
}

// ---------------- GEMM0: h0 = relu(x @ W0 + b0), write bf16 to two buffers ----------------
__global__ __launch_bounds__(256) void k_gemm0(const float* __restrict__ X,
                                               const unsigned short* __restrict__ Wt,
                                               const float* __restrict__ b0,
                                               unsigned* __restrict__ Ha,
                                               unsigned* __restrict__ Hb, int n){
  __shared__ __attribute__((aligned(16))) char lds[33792];
  char* ldsA = lds;           // 64 rows x 64 k bf16 = 8192 B (row stride 128 B)
  char* ldsW = lds + 8192;    // 128 c x 64 k bf16 = 16384 B
  float* ldsO = (float*)lds;  // 64 x 132 f32 (reused after compute)
  int t = threadIdx.x;
  int w = t >> 6, lane = t & 63;
  int rowBase = blockIdx.x * 64;
  f4 acc[8];
  #pragma unroll
  for (int i = 0; i < 8; i++) acc[i] = (f4)0.f;

  for (int kk = 0; kk < 8; kk++){
    #pragma unroll
    for (int iter = 0; iter < 2; iter++){
      int r = t / 8 + iter * 32;
      int kc = (t % 8) * 8;
      int grow = rowBase + r;
      float4 f0 = {0,0,0,0}, f1 = {0,0,0,0};
      if (grow < n){
        const float4* p = (const float4*)(X + (size_t)grow * FIN + kk * 64 + kc);
        f0 = p[0]; f1 = p[1];
      }
      u4 pv = { pack2(f0.x, f0.y), pack2(f0.z, f0.w), pack2(f1.x, f1.y), pack2(f1.z, f1.w) };
      *(u4*)(ldsA + r * 128 + ((kc * 2) ^ ((r & 7) << 4))) = pv;
    }
    #pragma unroll
    for (int iter = 0; iter < 4; iter++){
      int c = t / 8 + iter * 32;
      int kc = (t % 8) * 8;
      bh8 v = *(const bh8*)(Wt + (size_t)c * FIN + kk * 64 + kc);
      *(bh8*)(ldsW + c * 128 + ((kc * 2) ^ ((c & 7) << 4))) = v;
    }
    __syncthreads();
    int rowf = (w << 4) + (lane & 15);
    #pragma unroll
    for (int ks = 0; ks < 2; ks++){
      bh8 fa = *(const bh8*)(ldsA + rowf * 128 + ((ks * 64 + (lane >> 4) * 16) ^ ((rowf & 7) << 4)));
      #pragma unroll
      for (int ct = 0; ct < 8; ct++){
        int colf = (ct << 4) + (lane & 15);
        bh8 fb = *(const bh8*)(ldsW + colf * 128 + ((ks * 64 + (lane >> 4) * 16) ^ ((colf & 7) << 4)));
        acc[ct] = __builtin_amdgcn_mfma_f32_16x16x32_bf16(fa, fb, acc[ct], 0, 0, 0);
      }
    }
    __syncthreads();
  }
  #pragma unroll
  for (int ct = 0; ct < 8; ct++){
    int colf = (ct << 4) + (lane & 15);
    float bb = b0[colf];
    #pragma unroll
    for (int i = 0; i < 4; i++){
      int r = (w << 4) + ((lane >> 4) << 2) + i;
      float v = acc[ct][i] + bb;
      ldsO[r * 132 + colf] = v > 0.f ? v : 0.f;
    }
  }
  __syncthreads();
  #pragma unroll
  for (int iter = 0; iter < 4; iter++){
    int r = iter * 16 + t / 16;
    int c8 = (t % 16) * 8;
    int grow = rowBase + r;
    if (grow < n){
      float* p = &ldsO[r * 132 + c8];
      u4 pv = { pack2(p[0], p[1]), pack2(p[2], p[3]), pack2(p[4], p[5]), pack2(p[6], p[7]) };
      *(u4*)(Ha + (size_t)grow * 64 + (t % 16) * 4) = pv;
      *(u4*)(Hb + (size_t)grow * 64 + (t % 16) * 4) = pv;
    }
  }
}

// ---------------- fused layer v4: quad-owns-row gather, quad-uniform edge loads ----------------
// Hout = relu((1-beta)*T + beta*(T @ W)),  T = 0.9*(A h) + 0.1*x0
__global__ __launch_bounds__(256) void k_layer(const unsigned* __restrict__ Hin,
                                               const unsigned* __restrict__ X0,
                                               const int* __restrict__ offs,
                                               const u2* __restrict__ epk,
                                               const unsigned short* __restrict__ Wt,
                                               float beta,
                                               unsigned* __restrict__ Hout, int n){
  __shared__ __attribute__((aligned(16))) char ldsA[16384];  // 64 x 128 bf16, stride 256 B, swizzled
  int t = threadIdx.x;
  int w = t >> 6, lane = t & 63;
  int q = lane >> 4, l16 = lane & 15;
  int rowBase = blockIdx.x * 64;

  // gather: quad q of wave w owns rows (w*16 + rr*4 + q).  All 16 lanes of the quad
  // read the SAME edge record (quad-uniform address -> HW broadcast, L1-hot) and
  // each lane gathers its 16B slice of the source row.  No shfl/LDS on the chain.
  #pragma unroll
  for (int rr = 0; rr < 4; rr++){
    int lr = (w << 4) + (rr << 2) + q;
    int d = rowBase + lr;
    bool act = d < n;
    int e0 = act ? offs[d] : 0;
    int e1 = act ? offs[d + 1] : 0;
    float a0=0.f,a1=0.f,a2=0.f,a3=0.f,a4=0.f,a5=0.f,a6=0.f,a7=0.f;
    int e = e0;
    for (; e + 7 < e1; e += 8){
      #pragma unroll
      for (int j = 0; j < 8; j++){
        u2 pe = epk[e + j];
        float wf = __uint_as_float(pe.y);
        u4 r = *(const u4*)(Hin + (size_t)pe.x * 64 + l16 * 4);
        a0 += wf * bflo(r.x); a1 += wf * bfhi(r.x);
        a2 += wf * bflo(r.y); a3 += wf * bfhi(r.y);
        a4 += wf * bflo(r.z); a5 += wf * bfhi(r.z);
        a6 += wf * bflo(r.w); a7 += wf * bfhi(r.w);
      }
    }
    for (; e < e1; e++){
      u2 pe = epk[e];
      float wf = __uint_as_float(pe.y);
      u4 r = *(const u4*)(Hin + (size_t)pe.x * 64 + l16 * 4);
      a0 += wf * bflo(r.x); a1 += wf * bfhi(r.x);
      a2 += wf * bflo(r.y); a3 += wf * bfhi(r.y);
      a4 += wf * bflo(r.z); a5 += wf * bfhi(r.z);
      a6 += wf * bflo(r.w); a7 += wf * bfhi(r.w);
    }
    if (act){
      u4 xp = *(const u4*)(X0 + (size_t)d * 64 + l16 * 4);
      float v0 = 0.9f*a0 + 0.1f*bflo(xp.x), v1 = 0.9f*a1 + 0.1f*bfhi(xp.x);
      float v2 = 0.9f*a2 + 0.1f*bflo(xp.y), v3 = 0.9f*a3 + 0.1f*bfhi(xp.y);
      float v4 = 0.9f*a4 + 0.1f*bflo(xp.z), v5 = 0.9f*a5 + 0.1f*bfhi(xp.z);
      float v6 = 0.9f*a6 + 0.1f*bflo(xp.w), v7 = 0.9f*a7 + 0.1f*bfhi(xp.w);
      u4 ov = { pack2(v0,v1), pack2(v2,v3), pack2(v4,v5), pack2(v6,v7) };
      *(u4*)(ldsA + lr * 256 + ((l16 * 16) ^ ((lr & 7) << 4))) = ov;
    }
  }
  // no barrier: the MFMA A-fragment reads only this wave's own 16 rows

  f4 acc[8];
  #pragma unroll
  for (int i = 0; i < 8; i++) acc[i] = (f4)0.f;
  int rowf = (w << 4) + l16;
  #pragma unroll
  for (int ks = 0; ks < 4; ks++){
    bh8 fa = *(const bh8*)(ldsA + rowf * 256 + ((ks * 64 + q * 16) ^ ((rowf & 7) << 4)));
    #pragma unroll
    for (int ct = 0; ct < 8; ct++){
      int colf = (ct << 4) + l16;
      bh8 fb = *(const bh8*)(Wt + (size_t)colf * HD + ks * 32 + q * 8);
      acc[ct] = __builtin_amdgcn_mfma_f32_16x16x32_bf16(fa, fb, acc[ct], 0, 0, 0);
    }
  }

  // epilogue: identity-mix from own ldsA rows, relu, write bf16 back into own ldsA rows
  #pragma unroll
  for (int ct = 0; ct < 8; ct++){
    int colf = (ct << 4) + l16;
    #pragma unroll
    for (int i = 0; i < 4; i++){
      int r = (w << 4) + (q << 2) + i;
      char* addr = ldsA + r * 256 + ((colf * 2) ^ ((r & 7) << 4));
      unsigned short tv = *(const unsigned short*)addr;
      float tf = __uint_as_float(((unsigned)tv) << 16);
      float v = (1.f - beta) * tf + beta * acc[ct][i];
      *(unsigned short*)addr = f2bf(v > 0.f ? v : 0.f);
    }
  }
  __syncthreads();

  // coalesced bf16 store
  #pragma unroll
  for (int iter = 0; iter < 4; iter++){
    int r = iter * 16 + t / 16;
    int kc = (t % 16) * 8;
    int grow = rowBase + r;
    if (grow < n){
      bh8 v = *(const bh8*)(ldsA + r * 256 + ((kc * 2) ^ ((r & 7) << 4)));
      *(bh8*)((unsigned short*)Hout + (size_t)grow * HD + kc) = v;
    }
  }
}

// ---------------- head + log_softmax: MFMA 64x48 tile, in-register softmax ----------------
__global__ __launch_bounds__(256) void k_final(const unsigned* __restrict__ H,
                                               const unsigned short* __restrict__ W1t, // [48][128]
                                               const float* __restrict__ b1,
                                               float* __restrict__ out, int n){
  __shared__ __attribute__((aligned(16))) char lds[16384 + 12288];
  char* ldsA = lds;            // 64 x 128 bf16, row stride 256 B, swizzled
  char* ldsW = lds + 16384;    // 48 x 128 bf16
  int t = threadIdx.x;
  int w = t >> 6, lane = t & 63;
  int l15 = lane & 15;
  int rowBase = blockIdx.x * 64;
  const unsigned short* Hs = (const unsigned short*)H;

  #pragma unroll
  for (int iter = 0; iter < 4; iter++){
    int r = t / 16 + iter * 16;
    int kc = (t % 16) * 8;
    int grow = rowBase + r;
    bh8 v = (bh8)(short)0;
    if (grow < n) v = *(const bh8*)(Hs + (size_t)grow * HD + kc);
    *(bh8*)(ldsA + r * 256 + ((kc * 2) ^ ((r & 7) << 4))) = v;
  }
  #pragma unroll
  for (int iter = 0; iter < 3; iter++){
    int c = t / 16 + iter * 16;
    int kc = (t % 16) * 8;
    bh8 v = *(const bh8*)(W1t + (size_t)c * HD + kc);
    *(bh8*)(ldsW + c * 256 + ((kc * 2) ^ ((c & 7) << 4))) = v;
  }
  __syncthreads();

  f4 acc[3];
  #pragma unroll
  for (int i = 0; i < 3; i++) acc[i] = (f4)0.f;
  int rowf = (w << 4) + l15;
  #pragma unroll
  for (int ks = 0; ks < 4; ks++){
    bh8 fa = *(const bh8*)(ldsA + rowf * 256 + ((ks * 64 + (lane >> 4) * 16) ^ ((rowf & 7) << 4)));
    #pragma unroll
    for (int ct = 0; ct < 3; ct++){
      int colf = (ct << 4) + l15;
      bh8 fb = *(const bh8*)(ldsW + colf * 256 + ((ks * 64 + (lane >> 4) * 16) ^ ((colf & 7) << 4)));
      acc[ct] = __builtin_amdgcn_mfma_f32_16x16x32_bf16(fa, fb, acc[ct], 0, 0, 0);
    }
  }

  float bias0 = b1[l15];
  float bias1 = b1[16 + l15];
  bool v2ok = (l15 < 8);
  float bias2 = v2ok ? b1[32 + l15] : 0.f;

  #pragma unroll
  for (int i = 0; i < 4; i++){
    int r = rowBase + (w << 4) + ((lane >> 4) << 2) + i;
    float v0 = acc[0][i] + bias0;
    float v1 = acc[1][i] + bias1;
    float v2 = v2ok ? (acc[2][i] + bias2) : -1e30f;
    float m = fmaxf(fmaxf(v0, v1), v2);
    #pragma unroll
    for (int off = 1; off < 16; off <<= 1) m = fmaxf(m, __shfl_xor(m, off));
    float e0 = __expf(v0 - m), e1 = __expf(v1 - m);
    float e2 = v2ok ? __expf(v2 - m) : 0.f;
    float s = e0 + e1 + e2;
    #pragma unroll
    for (int off = 1; off < 16; off <<= 1) s += __shfl_xor(s, off);
    float ls = m + __logf(s);
    if (r < n){
      out[(size_t)r * NC + l15] = v0 - ls;
      out[(size_t)r * NC + 16 + l15] = v1 - ls;
      if (v2ok) out[(size_t)r * NC + 32 + l15] = v2 - ls;
    }
  }
}

extern "C" void kernel_launch(void* const* d_in, const int* in_sizes, int n_in,
                              void* d_out, int out_size, void* d_ws, size_t ws_size,
                              hipStream_t stream){
  const float* x  = (const float*)d_in[0];
  const int*   ei = (const int*)d_in[1];
  const float* ew = (const float*)d_in[2];
  const float* W0 = (const float*)d_in[3];
  const float* b0 = (const float*)d_in[4];
  const float* cW = (const float*)d_in[5];
  const float* W1 = (const float*)d_in[6];
  const float* b1 = (const float*)d_in[7];
  float* out = (float*)d_out;
  const int* src = ei;
  const int* dst = ei + NE;

  char* ws = (char*)d_ws;
  size_t off = 0;
  auto alloc = [&](size_t bytes) -> char* {
    char* p = ws + off;
    off += (bytes + 255) & ~(size_t)255;
    return p;
  };
  unsigned* x0b = (unsigned*)alloc((size_t)NN * 64 * 4);        // x0 bf16x2
  unsigned* hbA = (unsigned*)alloc((size_t)NN * 64 * 4);        // h ping
  unsigned* hbB = (unsigned*)alloc((size_t)NN * 64 * 4);        // h pong
  unsigned short* W0t = (unsigned short*)alloc((size_t)FIN * HD * 2);
  unsigned short* cWt = (unsigned short*)alloc((size_t)NL * HD * HD * 2);
  unsigned short* W1t = (unsigned short*)alloc((size_t)48 * HD * 2);
  int*   deg  = (int*)alloc((size_t)NN * 4);
  int*   offs = (int*)alloc((size_t)(NN + 1) * 4);
  int*   cur  = (int*)alloc((size_t)NN * 4);
  u2*    epk  = (u2*)alloc((size_t)NE * 8);

  (void)hipMemsetAsync(deg, 0, (size_t)NN * 4, stream);
  hipLaunchKernelGGL(k_deg, dim3(2048), dim3(256), 0, stream, dst, deg, NE);
  hipLaunchKernelGGL(k_scan, dim3(1), dim3(1024), 0, stream, deg, offs, cur, NN);
  hipLaunchKernelGGL(k_scatter, dim3(1024), dim3(256), 0, stream, src, dst, ew, cur, epk, NE);
  hipLaunchKernelGGL(k_twt, dim3(256), dim3(256), 0, stream, W0, W0t, FIN, HD, HD);
  for (int l = 0; l < NL; l++)
    hipLaunchKernelGGL(k_twt, dim3(64), dim3(256), 0, stream,
                       cW + (size_t)l * HD * HD, cWt + (size_t)l * HD * HD, HD, HD, HD);
  hipLaunchKernelGGL(k_twt, dim3(24), dim3(256), 0, stream, W1, W1t, HD, NC, 48);

  int gblocks = (NN + 63) / 64;
  hipLaunchKernelGGL(k_gemm0, dim3(gblocks), dim3(256), 0, stream, x, W0t, b0, x0b, hbA, NN);
  for (int l = 0; l < NL; l++){
    float beta = logf(0.5f / (float)(l + 1) + 1.0f);
    const unsigned* hin = (l & 1) ? hbB : hbA;
    unsigned* hout = (l & 1) ? hbA : hbB;
    hipLaunchKernelGGL(k_layer, dim3(gblocks), dim3(256), 0, stream,
                       hin, x0b, offs, epk, cWt + (size_t)l * HD * HD, beta, hout, NN);
  }
  hipLaunchKernelGGL(k_final, dim3(gblocks), dim3(256), 0, stream, hbA, W1t, b1, out, NN);
}

// Round 8
// 1172.733 us; speedup vs baseline: 1.0614x; 1.0614x over previous
//
#include <hip/hip_runtime.h>
#include <hip/hip_bf16.h>
#include <cmath>

#define NN 100000
#define NE 1600000
#define FIN 512
#define HD 128
#define NC 40
#define NL 8
#define SCB 512   // scatter blocks inside fused kernel

typedef __attribute__((ext_vector_type(8))) short bh8;
typedef __attribute__((ext_vector_type(4))) float f4;
typedef __attribute__((ext_vector_type(4))) unsigned int u4;
typedef __attribute__((ext_vector_type(2))) unsigned int u2;

__device__ __forceinline__ float bflo(unsigned p){ return __uint_as_float(p << 16); }
__device__ __forceinline__ float bfhi(unsigned p){ return __uint_as_float(p & 0xffff0000u); }
__device__ __forceinline__ unsigned short f2bf(float f){
  unsigned u = __float_as_uint(f);
  u += 0x7fffu + ((u >> 16) & 1u);
  return (unsigned short)(u >> 16);
}
__device__ __forceinline__ unsigned pack2(float a, float b){
  return (unsigned)f2bf(a) | ((unsigned)f2bf(b) << 16);
}

// ---------------- CSR build ----------------
__global__ void k_deg(const int* __restrict__ dst, int* __restrict__ deg, int e){
  for (int i = blockIdx.x * blockDim.x + threadIdx.x; i < e; i += gridDim.x * blockDim.x)
    atomicAdd(&deg[dst[i]], 1);
}

__global__ void k_scan(const int* __restrict__ deg, int* __restrict__ offs,
                       int* __restrict__ cur, int n){
  __shared__ int wsum[16];
  __shared__ int carry;
  int t = threadIdx.x, lane = t & 63, wid = t >> 6;
  if (t == 0) carry = 0;
  __syncthreads();
  for (int base = 0; base < n; base += 1024){
    int idx = base + t;
    int v = (idx < n) ? deg[idx] : 0;
    int orig = v;
    #pragma unroll
    for (int off = 1; off < 64; off <<= 1){
      int u = __shfl_up(v, off);
      if (lane >= off) v += u;
    }
    if (lane == 63) wsum[wid] = v;
    __syncthreads();
    if (wid == 0){
      int s = (lane < 16) ? wsum[lane] : 0;
      #pragma unroll
      for (int off = 1; off < 16; off <<= 1){
        int u = __shfl_up(s, off);
        if (lane >= off) s += u;
      }
      if (lane < 16) wsum[lane] = s;
    }
    __syncthreads();
    int wexcl = (wid == 0) ? 0 : wsum[wid - 1];
    int excl = carry + wexcl + (v - orig);
    if (idx < n){ offs[idx] = excl; cur[idx] = excl; }
    int ctot = wsum[15];
    __syncthreads();
    if (t == 0) carry += ctot;
    __syncthreads();
  }
  if (t == 0) offs[n] = carry;
}

// ---------------- weight transpose+cast: out[c][k] = bf16(in[k][c]) ----------------
__global__ void k_twt(const float* __restrict__ in, unsigned short* __restrict__ out,
                      int K, int C, int Cpad){
  int total = Cpad * K;
  for (int i = blockIdx.x * blockDim.x + threadIdx.x; i < total; i += gridDim.x * blockDim.x){
    int c = i / K, k = i % K;
    float v = (c < C) ? in[(size_t)k * C + c] : 0.f;
    out[i] = f2bf(v);
  }
}

// ---------------- fused: scatter (blocks 0..SCB-1) + GEMM0 (rest) ----------------
__global__ __launch_bounds__(256) void k_g0sc(const float* __restrict__ X,
                                              const unsigned short* __restrict__ Wt,
                                              const float* __restrict__ b0,
                                              unsigned* __restrict__ Ha,
                                              unsigned* __restrict__ Hb, int n,
                                              const int* __restrict__ src,
                                              const int* __restrict__ dst,
                                              const float* __restrict__ wgt,
                                              int* __restrict__ cur,
                                              u2* __restrict__ epk, int e){
  __shared__ __attribute__((aligned(16))) char lds[33792];
  if ((int)blockIdx.x < SCB){
    // ---- scatter path ----
    int stride = SCB * 256;
    int i = blockIdx.x * 256 + threadIdx.x;
    for (; i + 3 * stride < e; i += 4 * stride){
      int i0 = i, i1 = i + stride, i2 = i + 2 * stride, i3 = i + 3 * stride;
      int d0 = dst[i0], d1 = dst[i1], d2 = dst[i2], d3 = dst[i3];
      int p0 = atomicAdd(&cur[d0], 1);
      int p1 = atomicAdd(&cur[d1], 1);
      int p2 = atomicAdd(&cur[d2], 1);
      int p3 = atomicAdd(&cur[d3], 1);
      u2 v0 = { (unsigned)src[i0], __float_as_uint(wgt[i0]) };
      u2 v1 = { (unsigned)src[i1], __float_as_uint(wgt[i1]) };
      u2 v2 = { (unsigned)src[i2], __float_as_uint(wgt[i2]) };
      u2 v3 = { (unsigned)src[i3], __float_as_uint(wgt[i3]) };
      epk[p0] = v0; epk[p1] = v1; epk[p2] = v2; epk[p3] = v3;
    }
    for (; i < e; i += stride){
      int d = dst[i];
      int p = atomicAdd(&cur[d], 1);
      u2 v = { (unsigned)src[i], __float_as_uint(wgt[i]) };
      epk[p] = v;
    }
    return;
  }
  // ---- GEMM0 path: h0 = relu(x @ W0 + b0) ----
  char* ldsA = lds;           // 64 rows x 64 k bf16 (row stride 128 B)
  char* ldsW = lds + 8192;    // 128 c x 64 k bf16
  float* ldsO = (float*)lds;  // 64 x 132 f32 (reuse)
  int t = threadIdx.x;
  int w = t >> 6, lane = t & 63;
  int rowBase = (blockIdx.x - SCB) * 64;
  f4 acc[8];
  #pragma unroll
  for (int i = 0; i < 8; i++) acc[i] = (f4)0.f;

  for (int kk = 0; kk < 8; kk++){
    #pragma unroll
    for (int iter = 0; iter < 2; iter++){
      int r = t / 8 + iter * 32;
      int kc = (t % 8) * 8;
      int grow = rowBase + r;
      float4 f0 = {0,0,0,0}, f1 = {0,0,0,0};
      if (grow < n){
        const float4* p = (const float4*)(X + (size_t)grow * FIN + kk * 64 + kc);
        f0 = p[0]; f1 = p[1];
      }
      u4 pv = { pack2(f0.x, f0.y), pack2(f0.z, f0.w), pack2(f1.x, f1.y), pack2(f1.z, f1.w) };
      *(u4*)(ldsA + r * 128 + ((kc * 2) ^ ((r & 7) << 4))) = pv;
    }
    #pragma unroll
    for (int iter = 0; iter < 4; iter++){
      int c = t / 8 + iter * 32;
      int kc = (t % 8) * 8;
      bh8 v = *(const bh8*)(Wt + (size_t)c * FIN + kk * 64 + kc);
      *(bh8*)(ldsW + c * 128 + ((kc * 2) ^ ((c & 7) << 4))) = v;
    }
    __syncthreads();
    int rowf = (w << 4) + (lane & 15);
    #pragma unroll
    for (int ks = 0; ks < 2; ks++){
      bh8 fa = *(const bh8*)(ldsA + rowf * 128 + ((ks * 64 + (lane >> 4) * 16) ^ ((rowf & 7) << 4)));
      #pragma unroll
      for (int ct = 0; ct < 8; ct++){
        int colf = (ct << 4) + (lane & 15);
        bh8 fb = *(const bh8*)(ldsW + colf * 128 + ((ks * 64 + (lane >> 4) * 16) ^ ((colf & 7) << 4)));
        acc[ct] = __builtin_amdgcn_mfma_f32_16x16x32_bf16(fa, fb, acc[ct], 0, 0, 0);
      }
    }
    __syncthreads();
  }
  #pragma unroll
  for (int ct = 0; ct < 8; ct++){
    int colf = (ct << 4) + (lane & 15);
    float bb = b0[colf];
    #pragma unroll
    for (int i = 0; i < 4; i++){
      int r = (w << 4) + ((lane >> 4) << 2) + i;
      float v = acc[ct][i] + bb;
      ldsO[r * 132 + colf] = v > 0.f ? v : 0.f;
    }
  }
  __syncthreads();
  #pragma unroll
  for (int iter = 0; iter < 4; iter++){
    int r = iter * 16 + t / 16;
    int c8 = (t % 16) * 8;
    int grow = rowBase + r;
    if (grow < n){
      float* p = &ldsO[r * 132 + c8];
      u4 pv = { pack2(p[0], p[1]), pack2(p[2], p[3]), pack2(p[4], p[5]), pack2(p[6], p[7]) };
      *(u4*)(Ha + (size_t)grow * 64 + (t % 16) * 4) = pv;
      *(u4*)(Hb + (size_t)grow * 64 + (t % 16) * 4) = pv;
    }
  }
}

// ---------------- fused layer v5: 8 waves, quad owns 2 rows, W from global ----------------
// Hout = relu((1-beta)*T + beta*(T @ W)),  T = 0.9*(A h) + 0.1*x0
__global__ __launch_bounds__(512) void k_layer(const unsigned* __restrict__ Hin,
                                               const unsigned* __restrict__ X0,
                                               const int* __restrict__ offs,
                                               const u2* __restrict__ epk,
                                               const unsigned short* __restrict__ Wt,
                                               float beta,
                                               unsigned* __restrict__ Hout, int n){
  __shared__ __attribute__((aligned(16))) char ldsA[16384];  // 64 x 128 bf16, stride 256 B, swizzled
  int t = threadIdx.x;
  int w = t >> 6, lane = t & 63;
  int q = lane >> 4, l16 = lane & 15;
  int quadId = (w << 2) + q;           // 0..31
  int rowBase = blockIdx.x * 64;

  // gather: quad quadId owns rows quadId*2 + rr (rr=0,1); all 16 lanes read the
  // SAME edge record (quad-uniform -> HW broadcast), each lane gathers its 16B slice.
  #pragma unroll
  for (int rr = 0; rr < 2; rr++){
    int lr = (quadId << 1) + rr;
    int d = rowBase + lr;
    bool act = d < n;
    int e0 = act ? offs[d] : 0;
    int e1 = act ? offs[d + 1] : 0;
    float a0=0.f,a1=0.f,a2=0.f,a3=0.f,a4=0.f,a5=0.f,a6=0.f,a7=0.f;
    int e = e0;
    for (; e + 7 < e1; e += 8){
      #pragma unroll
      for (int j = 0; j < 8; j++){
        u2 pe = epk[e + j];
        float wf = __uint_as_float(pe.y);
        u4 r = *(const u4*)(Hin + (size_t)pe.x * 64 + l16 * 4);
        a0 += wf * bflo(r.x); a1 += wf * bfhi(r.x);
        a2 += wf * bflo(r.y); a3 += wf * bfhi(r.y);
        a4 += wf * bflo(r.z); a5 += wf * bfhi(r.z);
        a6 += wf * bflo(r.w); a7 += wf * bfhi(r.w);
      }
    }
    for (; e < e1; e++){
      u2 pe = epk[e];
      float wf = __uint_as_float(pe.y);
      u4 r = *(const u4*)(Hin + (size_t)pe.x * 64 + l16 * 4);
      a0 += wf * bflo(r.x); a1 += wf * bfhi(r.x);
      a2 += wf * bflo(r.y); a3 += wf * bfhi(r.y);
      a4 += wf * bflo(r.z); a5 += wf * bfhi(r.z);
      a6 += wf * bflo(r.w); a7 += wf * bfhi(r.w);
    }
    u4 ov = { 0u, 0u, 0u, 0u };
    if (act){
      u4 xp = *(const u4*)(X0 + (size_t)d * 64 + l16 * 4);
      float v0 = 0.9f*a0 + 0.1f*bflo(xp.x), v1 = 0.9f*a1 + 0.1f*bfhi(xp.x);
      float v2 = 0.9f*a2 + 0.1f*bflo(xp.y), v3 = 0.9f*a3 + 0.1f*bfhi(xp.y);
      float v4 = 0.9f*a4 + 0.1f*bflo(xp.z), v5 = 0.9f*a5 + 0.1f*bfhi(xp.z);
      float v6 = 0.9f*a6 + 0.1f*bflo(xp.w), v7 = 0.9f*a7 + 0.1f*bfhi(xp.w);
      ov = (u4){ pack2(v0,v1), pack2(v2,v3), pack2(v4,v5), pack2(v6,v7) };
    }
    *(u4*)(ldsA + lr * 256 + ((l16 * 16) ^ ((lr & 7) << 4))) = ov;
  }
  __syncthreads();   // A-rows now cross waves

  // MFMA: wave w computes rows (w&3)*16..+16, cols (w>>2)*64..+64
  f4 acc[4];
  #pragma unroll
  for (int i = 0; i < 4; i++) acc[i] = (f4)0.f;
  int rowf = ((w & 3) << 4) + l16;
  int colBase = (w >> 2) << 6;
  #pragma unroll
  for (int ks = 0; ks < 4; ks++){
    bh8 fa = *(const bh8*)(ldsA + rowf * 256 + ((ks * 64 + q * 16) ^ ((rowf & 7) << 4)));
    #pragma unroll
    for (int ct = 0; ct < 4; ct++){
      int colf = colBase + (ct << 4) + l16;
      bh8 fb = *(const bh8*)(Wt + (size_t)colf * HD + ks * 32 + q * 8);
      acc[ct] = __builtin_amdgcn_mfma_f32_16x16x32_bf16(fa, fb, acc[ct], 0, 0, 0);
    }
  }

  // epilogue: identity-mix (T re-read from ldsA at same (r,c)), relu, write back bf16
  #pragma unroll
  for (int ct = 0; ct < 4; ct++){
    int colf = colBase + (ct << 4) + l16;
    #pragma unroll
    for (int i = 0; i < 4; i++){
      int r = ((w & 3) << 4) + (q << 2) + i;
      char* addr = ldsA + r * 256 + ((colf * 2) ^ ((r & 7) << 4));
      unsigned short tv = *(const unsigned short*)addr;
      float tf = __uint_as_float(((unsigned)tv) << 16);
      float v = (1.f - beta) * tf + beta * acc[ct][i];
      *(unsigned short*)addr = f2bf(v > 0.f ? v : 0.f);
    }
  }
  __syncthreads();

  // coalesced bf16 store: 64 rows x 16 chunks of 16B = 1024 chunks / 512 threads
  #pragma unroll
  for (int iter = 0; iter < 2; iter++){
    int r = iter * 32 + t / 16;
    int kc = (t % 16) * 8;
    int grow = rowBase + r;
    if (grow < n){
      bh8 v = *(const bh8*)(ldsA + r * 256 + ((kc * 2) ^ ((r & 7) << 4)));
      *(bh8*)((unsigned short*)Hout + (size_t)grow * HD + kc) = v;
    }
  }
}

// ---------------- head + log_softmax: MFMA 64x48 tile, in-register softmax ----------------
__global__ __launch_bounds__(256) void k_final(const unsigned* __restrict__ H,
                                               const unsigned short* __restrict__ W1t, // [48][128]
                                               const float* __restrict__ b1,
                                               float* __restrict__ out, int n){
  __shared__ __attribute__((aligned(16))) char lds[16384 + 12288];
  char* ldsA = lds;            // 64 x 128 bf16, row stride 256 B, swizzled
  char* ldsW = lds + 16384;    // 48 x 128 bf16
  int t = threadIdx.x;
  int w = t >> 6, lane = t & 63;
  int l15 = lane & 15;
  int rowBase = blockIdx.x * 64;
  const unsigned short* Hs = (const unsigned short*)H;

  #pragma unroll
  for (int iter = 0; iter < 4; iter++){
    int r = t / 16 + iter * 16;
    int kc = (t % 16) * 8;
    int grow = rowBase + r;
    bh8 v = (bh8)(short)0;
    if (grow < n) v = *(const bh8*)(Hs + (size_t)grow * HD + kc);
    *(bh8*)(ldsA + r * 256 + ((kc * 2) ^ ((r & 7) << 4))) = v;
  }
  #pragma unroll
  for (int iter = 0; iter < 3; iter++){
    int c = t / 16 + iter * 16;
    int kc = (t % 16) * 8;
    bh8 v = *(const bh8*)(W1t + (size_t)c * HD + kc);
    *(bh8*)(ldsW + c * 256 + ((kc * 2) ^ ((c & 7) << 4))) = v;
  }
  __syncthreads();

  f4 acc[3];
  #pragma unroll
  for (int i = 0; i < 3; i++) acc[i] = (f4)0.f;
  int rowf = (w << 4) + l15;
  #pragma unroll
  for (int ks = 0; ks < 4; ks++){
    bh8 fa = *(const bh8*)(ldsA + rowf * 256 + ((ks * 64 + (lane >> 4) * 16) ^ ((rowf & 7) << 4)));
    #pragma unroll
    for (int ct = 0; ct < 3; ct++){
      int colf = (ct << 4) + l15;
      bh8 fb = *(const bh8*)(ldsW + colf * 256 + ((ks * 64 + (lane >> 4) * 16) ^ ((colf & 7) << 4)));
      acc[ct] = __builtin_amdgcn_mfma_f32_16x16x32_bf16(fa, fb, acc[ct], 0, 0, 0);
    }
  }

  float bias0 = b1[l15];
  float bias1 = b1[16 + l15];
  bool v2ok = (l15 < 8);
  float bias2 = v2ok ? b1[32 + l15] : 0.f;

  #pragma unroll
  for (int i = 0; i < 4; i++){
    int r = rowBase + (w << 4) + ((lane >> 4) << 2) + i;
    float v0 = acc[0][i] + bias0;
    float v1 = acc[1][i] + bias1;
    float v2 = v2ok ? (acc[2][i] + bias2) : -1e30f;
    float m = fmaxf(fmaxf(v0, v1), v2);
    #pragma unroll
    for (int off = 1; off < 16; off <<= 1) m = fmaxf(m, __shfl_xor(m, off));
    float e0 = __expf(v0 - m), e1 = __expf(v1 - m);
    float e2 = v2ok ? __expf(v2 - m) : 0.f;
    float s = e0 + e1 + e2;
    #pragma unroll
    for (int off = 1; off < 16; off <<= 1) s += __shfl_xor(s, off);
    float ls = m + __logf(s);
    if (r < n){
      out[(size_t)r * NC + l15] = v0 - ls;
      out[(size_t)r * NC + 16 + l15] = v1 - ls;
      if (v2ok) out[(size_t)r * NC + 32 + l15] = v2 - ls;
    }
  }
}

extern "C" void kernel_launch(void* const* d_in, const int* in_sizes, int n_in,
                              void* d_out, int out_size, void* d_ws, size_t ws_size,
                              hipStream_t stream){
  const float* x  = (const float*)d_in[0];
  const int*   ei = (const int*)d_in[1];
  const float* ew = (const float*)d_in[2];
  const float* W0 = (const float*)d_in[3];
  const float* b0 = (const float*)d_in[4];
  const float* cW = (const float*)d_in[5];
  const float* W1 = (const float*)d_in[6];
  const float* b1 = (const float*)d_in[7];
  float* out = (float*)d_out;
  const int* src = ei;
  const int* dst = ei + NE;

  char* ws = (char*)d_ws;
  size_t off = 0;
  auto alloc = [&](size_t bytes) -> char* {
    char* p = ws + off;
    off += (bytes + 255) & ~(size_t)255;
    return p;
  };
  unsigned* x0b = (unsigned*)alloc((size_t)NN * 64 * 4);        // x0 bf16x2
  unsigned* hbA = (unsigned*)alloc((size_t)NN * 64 * 4);        // h ping
  unsigned* hbB = (unsigned*)alloc((size_t)NN * 64 * 4);        // h pong
  unsigned short* W0t = (unsigned short*)alloc((size_t)FIN * HD * 2);
  unsigned short* cWt = (unsigned short*)alloc((size_t)NL * HD * HD * 2);
  unsigned short* W1t = (unsigned short*)alloc((size_t)48 * HD * 2);
  int*   deg  = (int*)alloc((size_t)NN * 4);
  int*   offs = (int*)alloc((size_t)(NN + 1) * 4);
  int*   cur  = (int*)alloc((size_t)NN * 4);
  u2*    epk  = (u2*)alloc((size_t)NE * 8);

  (void)hipMemsetAsync(deg, 0, (size_t)NN * 4, stream);
  hipLaunchKernelGGL(k_deg, dim3(2048), dim3(256), 0, stream, dst, deg, NE);
  hipLaunchKernelGGL(k_scan, dim3(1), dim3(1024), 0, stream, deg, offs, cur, NN);
  hipLaunchKernelGGL(k_twt, dim3(256), dim3(256), 0, stream, W0, W0t, FIN, HD, HD);
  for (int l = 0; l < NL; l++)
    hipLaunchKernelGGL(k_twt, dim3(64), dim3(256), 0, stream,
                       cW + (size_t)l * HD * HD, cWt + (size_t)l * HD * HD, HD, HD, HD);
  hipLaunchKernelGGL(k_twt, dim3(24), dim3(256), 0, stream, W1, W1t, HD, NC, 48);

  int gblocks = (NN + 63) / 64;
  // fused: scatter (SCB blocks) + gemm0 (gblocks)
  hipLaunchKernelGGL(k_g0sc, dim3(SCB + gblocks), dim3(256), 0, stream,
                     x, W0t, b0, x0b, hbA, NN, src, dst, ew, cur, epk, NE);
  for (int l = 0; l < NL; l++){
    float beta = logf(0.5f / (float)(l + 1) + 1.0f);
    const unsigned* hin = (l & 1) ? hbB : hbA;
    unsigned* hout = (l & 1) ? hbA : hbB;
    hipLaunchKernelGGL(k_layer, dim3(gblocks), dim3(512), 0, stream,
                       hin, x0b, offs, epk, cWt + (size_t)l * HD * HD, beta, hout, NN);
  }
  hipLaunchKernelGGL(k_final, dim3(gblocks), dim3(256), 0, stream, hbA, W1t, b1, out, NN);
}

// Round 9
// 1000.028 us; speedup vs baseline: 1.2447x; 1.1727x over previous
//
#include <hip/hip_runtime.h>
#include <hip/hip_bf16.h>
#include <cmath>

#define NN 100000
#define NE 1600000
#define FIN 512
#define HD 128
#define NC 40
#define NL 8
#define NBK 196                      // ceil(NN / 512) buckets of 512 dsts
#define P1B 256                      // partition blocks
#define CHUNK ((NE + P1B - 1) / P1B) // 6250 edges per partition block

typedef __attribute__((ext_vector_type(8))) short bh8;
typedef __attribute__((ext_vector_type(4))) float f4;
typedef __attribute__((ext_vector_type(4))) unsigned int u4;
typedef __attribute__((ext_vector_type(2))) unsigned int u2;

__device__ __forceinline__ float bflo(unsigned p){ return __uint_as_float(p << 16); }
__device__ __forceinline__ float bfhi(unsigned p){ return __uint_as_float(p & 0xffff0000u); }
__device__ __forceinline__ unsigned short f2bf(float f){
  unsigned u = __float_as_uint(f);
  u += 0x7fffu + ((u >> 16) & 1u);
  return (unsigned short)(u >> 16);
}
__device__ __forceinline__ unsigned pack2(float a, float b){
  return (unsigned)f2bf(a) | ((unsigned)f2bf(b) << 16);
}

// ---------------- CSR build: radix partition by dst ----------------
__global__ __launch_bounds__(256) void k_hist(const int* __restrict__ dst,
                                              int* __restrict__ bcnt){
  __shared__ int h[256];
  int t = threadIdx.x;
  h[t] = 0;
  __syncthreads();
  int lo = blockIdx.x * CHUNK;
  int hi = lo + CHUNK < NE ? lo + CHUNK : NE;
  for (int i = lo + t; i < hi; i += 256)
    atomicAdd(&h[dst[i] >> 9], 1);
  __syncthreads();
  if (h[t]) atomicAdd(&bcnt[t], h[t]);
}

__global__ void k_bscan(const int* __restrict__ bcnt, int* __restrict__ gbase,
                        int* __restrict__ gcur, int* __restrict__ offs){
  int t = threadIdx.x;   // 64 threads
  int carry = 0;
  for (int base = 0; base < 256; base += 64){
    int v = bcnt[base + t];
    int orig = v;
    #pragma unroll
    for (int off = 1; off < 64; off <<= 1){
      int u = __shfl_up(v, off);
      if (t >= off) v += u;
    }
    int excl = carry + v - orig;
    gbase[base + t] = excl;
    gcur[base + t] = excl;
    carry += __shfl(v, 63);
  }
  if (t == 0){ gbase[256] = carry; offs[NN] = NE; }
}

__global__ __launch_bounds__(256) void k_part(const int* __restrict__ src,
                                              const int* __restrict__ dst,
                                              const float* __restrict__ w,
                                              int* __restrict__ gcur,
                                              u2* __restrict__ tmp){
  __shared__ int h[256];
  __shared__ int base[256];
  int t = threadIdx.x;
  h[t] = 0;
  __syncthreads();
  int lo = blockIdx.x * CHUNK;
  int hi = lo + CHUNK < NE ? lo + CHUNK : NE;
  for (int i = lo + t; i < hi; i += 256)
    atomicAdd(&h[dst[i] >> 9], 1);
  __syncthreads();
  int cnt = h[t];
  if (cnt) base[t] = atomicAdd(&gcur[t], cnt);
  h[t] = 0;
  __syncthreads();
  for (int i = lo + t; i < hi; i += 256){
    int d = dst[i];
    int bk = d >> 9;
    int r = atomicAdd(&h[bk], 1);
    u2 v = { (unsigned)src[i] | ((unsigned)(d & 511) << 17), __float_as_uint(w[i]) };
    tmp[base[bk] + r] = v;
  }
}

__global__ __launch_bounds__(256) void k_place(const u2* __restrict__ tmp,
                                               const int* __restrict__ gbase,
                                               int* __restrict__ offs,
                                               u2* __restrict__ epk){
  __shared__ int h[512];
  __shared__ int lofs[512];
  int b = blockIdx.x;
  int t = threadIdx.x;
  int e0 = gbase[b], e1 = gbase[b + 1];
  h[t] = 0; h[t + 256] = 0;
  __syncthreads();
  for (int i = e0 + t; i < e1; i += 256)
    atomicAdd(&h[tmp[i].x >> 17], 1);
  __syncthreads();
  if (t < 64){
    int carry = 0;
    for (int base = 0; base < 512; base += 64){
      int v = h[base + t];
      int orig = v;
      #pragma unroll
      for (int off = 1; off < 64; off <<= 1){
        int u = __shfl_up(v, off);
        if (t >= off) v += u;
      }
      lofs[base + t] = carry + v - orig;
      carry += __shfl(v, 63);
    }
  }
  __syncthreads();
  int d = b * 512 + t;
  if (d < NN) offs[d] = e0 + lofs[t];
  int d2 = b * 512 + 256 + t;
  if (d2 < NN) offs[d2] = e0 + lofs[256 + t];
  h[t] = 0; h[t + 256] = 0;
  __syncthreads();
  for (int i = e0 + t; i < e1; i += 256){
    u2 v = tmp[i];
    int d9 = v.x >> 17;
    int r = atomicAdd(&h[d9], 1);
    u2 o = { v.x & 0x1FFFFu, v.y };
    epk[e0 + lofs[d9] + r] = o;
  }
}

// ---------------- all weight transposes in one kernel ----------------
// layout: [0, FIN*HD) = W0t[c][k]; then NL*HD*HD cWt; then 48*HD W1t
__global__ void k_twt_all(const float* __restrict__ W0, const float* __restrict__ cW,
                          const float* __restrict__ W1, unsigned short* __restrict__ out){
  const int n0 = FIN * HD;
  const int n1 = NL * HD * HD;
  const int total = n0 + n1 + 48 * HD;
  for (int i = blockIdx.x * blockDim.x + threadIdx.x; i < total; i += gridDim.x * blockDim.x){
    float v;
    if (i < n0){
      int c = i / FIN, k = i % FIN;
      v = W0[(size_t)k * HD + c];
    } else if (i < n0 + n1){
      int j = i - n0;
      int l = j / (HD * HD), r = j % (HD * HD);
      int c = r / HD, k = r % HD;
      v = cW[(size_t)l * HD * HD + k * HD + c];
    } else {
      int j = i - n0 - n1;
      int c = j / HD, k = j % HD;
      v = (c < NC) ? W1[(size_t)k * NC + c] : 0.f;
    }
    out[i] = f2bf(v);
  }
}

// ---------------- GEMM0: h0 = relu(x @ W0 + b0), write bf16 to two buffers ----------------
__global__ __launch_bounds__(256) void k_gemm0(const float* __restrict__ X,
                                               const unsigned short* __restrict__ Wt,
                                               const float* __restrict__ b0,
                                               unsigned* __restrict__ Ha,
                                               unsigned* __restrict__ Hb, int n){
  __shared__ __attribute__((aligned(16))) char lds[33792];
  char* ldsA = lds;           // 64 rows x 64 k bf16 (row stride 128 B)
  char* ldsW = lds + 8192;    // 128 c x 64 k bf16
  float* ldsO = (float*)lds;  // 64 x 132 f32 (reuse)
  int t = threadIdx.x;
  int w = t >> 6, lane = t & 63;
  int rowBase = blockIdx.x * 64;
  f4 acc[8];
  #pragma unroll
  for (int i = 0; i < 8; i++) acc[i] = (f4)0.f;

  for (int kk = 0; kk < 8; kk++){
    #pragma unroll
    for (int iter = 0; iter < 2; iter++){
      int r = t / 8 + iter * 32;
      int kc = (t % 8) * 8;
      int grow = rowBase + r;
      float4 f0 = {0,0,0,0}, f1 = {0,0,0,0};
      if (grow < n){
        const float4* p = (const float4*)(X + (size_t)grow * FIN + kk * 64 + kc);
        f0 = p[0]; f1 = p[1];
      }
      u4 pv = { pack2(f0.x, f0.y), pack2(f0.z, f0.w), pack2(f1.x, f1.y), pack2(f1.z, f1.w) };
      *(u4*)(ldsA + r * 128 + ((kc * 2) ^ ((r & 7) << 4))) = pv;
    }
    #pragma unroll
    for (int iter = 0; iter < 4; iter++){
      int c = t / 8 + iter * 32;
      int kc = (t % 8) * 8;
      bh8 v = *(const bh8*)(Wt + (size_t)c * FIN + kk * 64 + kc);
      *(bh8*)(ldsW + c * 128 + ((kc * 2) ^ ((c & 7) << 4))) = v;
    }
    __syncthreads();
    int rowf = (w << 4) + (lane & 15);
    #pragma unroll
    for (int ks = 0; ks < 2; ks++){
      bh8 fa = *(const bh8*)(ldsA + rowf * 128 + ((ks * 64 + (lane >> 4) * 16) ^ ((rowf & 7) << 4)));
      #pragma unroll
      for (int ct = 0; ct < 8; ct++){
        int colf = (ct << 4) + (lane & 15);
        bh8 fb = *(const bh8*)(ldsW + colf * 128 + ((ks * 64 + (lane >> 4) * 16) ^ ((colf & 7) << 4)));
        acc[ct] = __builtin_amdgcn_mfma_f32_16x16x32_bf16(fa, fb, acc[ct], 0, 0, 0);
      }
    }
    __syncthreads();
  }
  #pragma unroll
  for (int ct = 0; ct < 8; ct++){
    int colf = (ct << 4) + (lane & 15);
    float bb = b0[colf];
    #pragma unroll
    for (int i = 0; i < 4; i++){
      int r = (w << 4) + ((lane >> 4) << 2) + i;
      float v = acc[ct][i] + bb;
      ldsO[r * 132 + colf] = v > 0.f ? v : 0.f;
    }
  }
  __syncthreads();
  #pragma unroll
  for (int iter = 0; iter < 4; iter++){
    int r = iter * 16 + t / 16;
    int c8 = (t % 16) * 8;
    int grow = rowBase + r;
    if (grow < n){
      float* p = &ldsO[r * 132 + c8];
      u4 pv = { pack2(p[0], p[1]), pack2(p[2], p[3]), pack2(p[4], p[5]), pack2(p[6], p[7]) };
      *(u4*)(Ha + (size_t)grow * 64 + (t % 16) * 4) = pv;
      *(u4*)(Hb + (size_t)grow * 64 + (t % 16) * 4) = pv;
    }
  }
}

// ---------------- fused layer v5: 8 waves, quad owns 2 rows, W from global ----------------
// Hout = relu((1-beta)*T + beta*(T @ W)),  T = 0.9*(A h) + 0.1*x0
__global__ __launch_bounds__(512) void k_layer(const unsigned* __restrict__ Hin,
                                               const unsigned* __restrict__ X0,
                                               const int* __restrict__ offs,
                                               const u2* __restrict__ epk,
                                               const unsigned short* __restrict__ Wt,
                                               float beta,
                                               unsigned* __restrict__ Hout, int n){
  __shared__ __attribute__((aligned(16))) char ldsA[16384];  // 64 x 128 bf16, stride 256 B, swizzled
  int t = threadIdx.x;
  int w = t >> 6, lane = t & 63;
  int q = lane >> 4, l16 = lane & 15;
  int quadId = (w << 2) + q;           // 0..31
  int rowBase = blockIdx.x * 64;

  #pragma unroll
  for (int rr = 0; rr < 2; rr++){
    int lr = (quadId << 1) + rr;
    int d = rowBase + lr;
    bool act = d < n;
    int e0 = act ? offs[d] : 0;
    int e1 = act ? offs[d + 1] : 0;
    float a0=0.f,a1=0.f,a2=0.f,a3=0.f,a4=0.f,a5=0.f,a6=0.f,a7=0.f;
    int e = e0;
    for (; e + 7 < e1; e += 8){
      #pragma unroll
      for (int j = 0; j < 8; j++){
        u2 pe = epk[e + j];
        float wf = __uint_as_float(pe.y);
        u4 r = *(const u4*)(Hin + (size_t)pe.x * 64 + l16 * 4);
        a0 += wf * bflo(r.x); a1 += wf * bfhi(r.x);
        a2 += wf * bflo(r.y); a3 += wf * bfhi(r.y);
        a4 += wf * bflo(r.z); a5 += wf * bfhi(r.z);
        a6 += wf * bflo(r.w); a7 += wf * bfhi(r.w);
      }
    }
    for (; e < e1; e++){
      u2 pe = epk[e];
      float wf = __uint_as_float(pe.y);
      u4 r = *(const u4*)(Hin + (size_t)pe.x * 64 + l16 * 4);
      a0 += wf * bflo(r.x); a1 += wf * bfhi(r.x);
      a2 += wf * bflo(r.y); a3 += wf * bfhi(r.y);
      a4 += wf * bflo(r.z); a5 += wf * bfhi(r.z);
      a6 += wf * bflo(r.w); a7 += wf * bfhi(r.w);
    }
    u4 ov = { 0u, 0u, 0u, 0u };
    if (act){
      u4 xp = *(const u4*)(X0 + (size_t)d * 64 + l16 * 4);
      float v0 = 0.9f*a0 + 0.1f*bflo(xp.x), v1 = 0.9f*a1 + 0.1f*bfhi(xp.x);
      float v2 = 0.9f*a2 + 0.1f*bflo(xp.y), v3 = 0.9f*a3 + 0.1f*bfhi(xp.y);
      float v4 = 0.9f*a4 + 0.1f*bflo(xp.z), v5 = 0.9f*a5 + 0.1f*bfhi(xp.z);
      float v6 = 0.9f*a6 + 0.1f*bflo(xp.w), v7 = 0.9f*a7 + 0.1f*bfhi(xp.w);
      ov = (u4){ pack2(v0,v1), pack2(v2,v3), pack2(v4,v5), pack2(v6,v7) };
    }
    *(u4*)(ldsA + lr * 256 + ((l16 * 16) ^ ((lr & 7) << 4))) = ov;
  }
  __syncthreads();

  // MFMA: wave w computes rows (w&3)*16..+16, cols (w>>2)*64..+64
  f4 acc[4];
  #pragma unroll
  for (int i = 0; i < 4; i++) acc[i] = (f4)0.f;
  int rowf = ((w & 3) << 4) + l16;
  int colBase = (w >> 2) << 6;
  #pragma unroll
  for (int ks = 0; ks < 4; ks++){
    bh8 fa = *(const bh8*)(ldsA + rowf * 256 + ((ks * 64 + q * 16) ^ ((rowf & 7) << 4)));
    #pragma unroll
    for (int ct = 0; ct < 4; ct++){
      int colf = colBase + (ct << 4) + l16;
      bh8 fb = *(const bh8*)(Wt + (size_t)colf * HD + ks * 32 + q * 8);
      acc[ct] = __builtin_amdgcn_mfma_f32_16x16x32_bf16(fa, fb, acc[ct], 0, 0, 0);
    }
  }

  #pragma unroll
  for (int ct = 0; ct < 4; ct++){
    int colf = colBase + (ct << 4) + l16;
    #pragma unroll
    for (int i = 0; i < 4; i++){
      int r = ((w & 3) << 4) + (q << 2) + i;
      char* addr = ldsA + r * 256 + ((colf * 2) ^ ((r & 7) << 4));
      unsigned short tv = *(const unsigned short*)addr;
      float tf = __uint_as_float(((unsigned)tv) << 16);
      float v = (1.f - beta) * tf + beta * acc[ct][i];
      *(unsigned short*)addr = f2bf(v > 0.f ? v : 0.f);
    }
  }
  __syncthreads();

  #pragma unroll
  for (int iter = 0; iter < 2; iter++){
    int r = iter * 32 + t / 16;
    int kc = (t % 16) * 8;
    int grow = rowBase + r;
    if (grow < n){
      bh8 v = *(const bh8*)(ldsA + r * 256 + ((kc * 2) ^ ((r & 7) << 4)));
      *(bh8*)((unsigned short*)Hout + (size_t)grow * HD + kc) = v;
    }
  }
}

// ---------------- head + log_softmax: MFMA 64x48 tile, in-register softmax ----------------
__global__ __launch_bounds__(256) void k_final(const unsigned* __restrict__ H,
                                               const unsigned short* __restrict__ W1t, // [48][128]
                                               const float* __restrict__ b1,
                                               float* __restrict__ out, int n){
  __shared__ __attribute__((aligned(16))) char lds[16384 + 12288];
  char* ldsA = lds;            // 64 x 128 bf16, row stride 256 B, swizzled
  char* ldsW = lds + 16384;    // 48 x 128 bf16
  int t = threadIdx.x;
  int w = t >> 6, lane = t & 63;
  int l15 = lane & 15;
  int rowBase = blockIdx.x * 64;
  const unsigned short* Hs = (const unsigned short*)H;

  #pragma unroll
  for (int iter = 0; iter < 4; iter++){
    int r = t / 16 + iter * 16;
    int kc = (t % 16) * 8;
    int grow = rowBase + r;
    bh8 v = (bh8)(short)0;
    if (grow < n) v = *(const bh8*)(Hs + (size_t)grow * HD + kc);
    *(bh8*)(ldsA + r * 256 + ((kc * 2) ^ ((r & 7) << 4))) = v;
  }
  #pragma unroll
  for (int iter = 0; iter < 3; iter++){
    int c = t / 16 + iter * 16;
    int kc = (t % 16) * 8;
    bh8 v = *(const bh8*)(W1t + (size_t)c * HD + kc);
    *(bh8*)(ldsW + c * 256 + ((kc * 2) ^ ((c & 7) << 4))) = v;
  }
  __syncthreads();

  f4 acc[3];
  #pragma unroll
  for (int i = 0; i < 3; i++) acc[i] = (f4)0.f;
  int rowf = (w << 4) + l15;
  #pragma unroll
  for (int ks = 0; ks < 4; ks++){
    bh8 fa = *(const bh8*)(ldsA + rowf * 256 + ((ks * 64 + (lane >> 4) * 16) ^ ((rowf & 7) << 4)));
    #pragma unroll
    for (int ct = 0; ct < 3; ct++){
      int colf = (ct << 4) + l15;
      bh8 fb = *(const bh8*)(ldsW + colf * 256 + ((ks * 64 + (lane >> 4) * 16) ^ ((colf & 7) << 4)));
      acc[ct] = __builtin_amdgcn_mfma_f32_16x16x32_bf16(fa, fb, acc[ct], 0, 0, 0);
    }
  }

  float bias0 = b1[l15];
  float bias1 = b1[16 + l15];
  bool v2ok = (l15 < 8);
  float bias2 = v2ok ? b1[32 + l15] : 0.f;

  #pragma unroll
  for (int i = 0; i < 4; i++){
    int r = rowBase + (w << 4) + ((lane >> 4) << 2) + i;
    float v0 = acc[0][i] + bias0;
    float v1 = acc[1][i] + bias1;
    float v2 = v2ok ? (acc[2][i] + bias2) : -1e30f;
    float m = fmaxf(fmaxf(v0, v1), v2);
    #pragma unroll
    for (int off = 1; off < 16; off <<= 1) m = fmaxf(m, __shfl_xor(m, off));
    float e0 = __expf(v0 - m), e1 = __expf(v1 - m);
    float e2 = v2ok ? __expf(v2 - m) : 0.f;
    float s = e0 + e1 + e2;
    #pragma unroll
    for (int off = 1; off < 16; off <<= 1) s += __shfl_xor(s, off);
    float ls = m + __logf(s);
    if (r < n){
      out[(size_t)r * NC + l15] = v0 - ls;
      out[(size_t)r * NC + 16 + l15] = v1 - ls;
      if (v2ok) out[(size_t)r * NC + 32 + l15] = v2 - ls;
    }
  }
}

extern "C" void kernel_launch(void* const* d_in, const int* in_sizes, int n_in,
                              void* d_out, int out_size, void* d_ws, size_t ws_size,
                              hipStream_t stream){
  const float* x  = (const float*)d_in[0];
  const int*   ei = (const int*)d_in[1];
  const float* ew = (const float*)d_in[2];
  const float* W0 = (const float*)d_in[3];
  const float* b0 = (const float*)d_in[4];
  const float* cW = (const float*)d_in[5];
  const float* W1 = (const float*)d_in[6];
  const float* b1 = (const float*)d_in[7];
  float* out = (float*)d_out;
  const int* src = ei;
  const int* dst = ei + NE;

  char* ws = (char*)d_ws;
  size_t off = 0;
  auto alloc = [&](size_t bytes) -> char* {
    char* p = ws + off;
    off += (bytes + 255) & ~(size_t)255;
    return p;
  };
  unsigned* x0b = (unsigned*)alloc((size_t)NN * 64 * 4);        // x0 bf16x2
  unsigned* hbA = (unsigned*)alloc((size_t)NN * 64 * 4);        // h ping
  unsigned* hbB = (unsigned*)alloc((size_t)NN * 64 * 4);        // h pong
  unsigned short* wbuf = (unsigned short*)alloc(((size_t)FIN * HD + (size_t)NL * HD * HD + 48 * HD) * 2);
  unsigned short* W0t = wbuf;
  unsigned short* cWt = wbuf + (size_t)FIN * HD;
  unsigned short* W1t = cWt + (size_t)NL * HD * HD;
  int*   offs  = (int*)alloc((size_t)(NN + 1) * 4);
  int*   bcnt  = (int*)alloc(256 * 4);
  int*   gbase = (int*)alloc(257 * 4);
  int*   gcur  = (int*)alloc(256 * 4);
  u2*    tmp   = (u2*)alloc((size_t)NE * 8);
  u2*    epk   = (u2*)alloc((size_t)NE * 8);

  (void)hipMemsetAsync(bcnt, 0, 256 * 4, stream);
  hipLaunchKernelGGL(k_hist, dim3(P1B), dim3(256), 0, stream, dst, bcnt);
  hipLaunchKernelGGL(k_bscan, dim3(1), dim3(64), 0, stream, bcnt, gbase, gcur, offs);
  hipLaunchKernelGGL(k_part, dim3(P1B), dim3(256), 0, stream, src, dst, ew, gcur, tmp);
  hipLaunchKernelGGL(k_place, dim3(NBK), dim3(256), 0, stream, tmp, gbase, offs, epk);
  hipLaunchKernelGGL(k_twt_all, dim3(256), dim3(256), 0, stream, W0, cW, W1, wbuf);

  int gblocks = (NN + 63) / 64;
  hipLaunchKernelGGL(k_gemm0, dim3(gblocks), dim3(256), 0, stream, x, W0t, b0, x0b, hbA, NN);
  for (int l = 0; l < NL; l++){
    float beta = logf(0.5f / (float)(l + 1) + 1.0f);
    const unsigned* hin = (l & 1) ? hbB : hbA;
    unsigned* hout = (l & 1) ? hbA : hbB;
    hipLaunchKernelGGL(k_layer, dim3(gblocks), dim3(512), 0, stream,
                       hin, x0b, offs, epk, cWt + (size_t)l * HD * HD, beta, hout, NN);
  }
  hipLaunchKernelGGL(k_final, dim3(gblocks), dim3(256), 0, stream, hbA, W1t, b1, out, NN);
}